// Round 1
// baseline (282.050 us; speedup 1.0000x reference)
//
#include <hip/hip_runtime.h>

// Problem constants (from reference): B=128, K=256, M=8, D=128
#define BB 128
#define KK 256
#define MM 8
#define DD 128
#define NROWS (BB * KK)       // 32768 query rows (b,k) flattened
#define ROW_TILE 64           // rows per block
#define CT 32                 // concepts per column tile
#define NCT (KK / CT)         // 8 column tiles
#define DCHUNK 16             // d-slice staged per P tile
#define NDC (DD / DCHUNK)     // 8
#define VSTR 68               // Vs row stride (64 rows + pad, 16B-aligned)
#define PSTR 260              // Ps row stride (256 cols + pad, 16B-aligned)

#define LAMBDA_T 20.0f
#define GAMMA_T 20.0f
#define MARGIN_T 0.05f

// LDS budget: Vs 128*68*4=34816 + Ps 16*260*4=16640 + 512 = 51968 B < 64 KB
__global__ __launch_bounds__(256, 2)
void mpcl_main(const float* __restrict__ V,       // (NROWS, D) row-major
               const int* __restrict__ labels,    // (NROWS)
               const float* __restrict__ P,       // (KK*MM, D) row-major
               float* __restrict__ acc_ws)        // [0]=masked loss sum, [1]=num_pos
{
    __shared__ float Vs[DD][VSTR];      // transposed: Vs[d][row]
    __shared__ float Ps[DCHUNK][PSTR];  // transposed: Ps[d][col]
    __shared__ float sh_denom[ROW_TILE];
    __shared__ float sh_simpos[ROW_TILE];

    const int tid = threadIdx.x;
    const int tr  = tid >> 5;   // 0..7  -> rows tr*8 .. tr*8+7
    const int tc  = tid & 31;   // 0..31 -> concept (ct*32 + tc)
    const int rowbase = blockIdx.x * ROW_TILE;

    if (tid < ROW_TILE) sh_denom[tid] = 0.0f;

    // ---- stage V tile (64 rows x 128 d), transpose into Vs[d][row] ----
    // lanes are d-contiguous -> fully coalesced 16B/lane global loads
#pragma unroll
    for (int it = 0; it < 8; ++it) {
        int idx = tid + it * 256;       // 0..2047
        int row = idx >> 5;             // 0..63
        int dj  = idx & 31;             // 0..31 -> d = dj*4
        float4 v = *(const float4*)(V + (size_t)(rowbase + row) * DD + dj * 4);
        Vs[dj * 4 + 0][row] = v.x;
        Vs[dj * 4 + 1][row] = v.y;
        Vs[dj * 4 + 2][row] = v.z;
        Vs[dj * 4 + 3][row] = v.w;
    }

    float denomp[8];
    float simposv[8];
#pragma unroll
    for (int r = 0; r < 8; ++r) { denomp[r] = 0.0f; simposv[r] = 0.0f; }

    for (int ct = 0; ct < NCT; ++ct) {
        float acc[8][8];
#pragma unroll
        for (int r = 0; r < 8; ++r)
#pragma unroll
            for (int m = 0; m < 8; ++m) acc[r][m] = 0.0f;

        for (int dc = 0; dc < NDC; ++dc) {
            __syncthreads();  // previous Ps consumers done (also covers Vs/denom init on first pass)
            // ---- stage P chunk: cols ct*256..+255, d dc*16..+15, transposed ----
#pragma unroll
            for (int it = 0; it < 4; ++it) {
                int idx = tid + it * 256;   // 0..1023
                int col = idx >> 2;         // 0..255
                int j   = idx & 3;          // d = j*4
                float4 p = *(const float4*)(P + (size_t)(ct * 256 + col) * DD
                                              + dc * DCHUNK + j * 4);
                Ps[j * 4 + 0][col] = p.x;
                Ps[j * 4 + 1][col] = p.y;
                Ps[j * 4 + 2][col] = p.z;
                Ps[j * 4 + 3][col] = p.w;
            }
            __syncthreads();

#pragma unroll
            for (int dd = 0; dd < DCHUNK; ++dd) {
                const int dg = dc * DCHUNK + dd;
                float4 vA = *(const float4*)&Vs[dg][tr * 8];
                float4 vB = *(const float4*)&Vs[dg][tr * 8 + 4];
                float4 pA = *(const float4*)&Ps[dd][tc * 8];
                float4 pB = *(const float4*)&Ps[dd][tc * 8 + 4];
                float vv[8] = {vA.x, vA.y, vA.z, vA.w, vB.x, vB.y, vB.z, vB.w};
                float pp[8] = {pA.x, pA.y, pA.z, pA.w, pB.x, pB.y, pB.z, pB.w};
#pragma unroll
                for (int r = 0; r < 8; ++r)
#pragma unroll
                    for (int m = 0; m < 8; ++m)
                        acc[r][m] = fmaf(vv[r], pp[m], acc[r][m]);
            }
        }

        // ---- Eq.6-8: softmax over M=8 + weighted sim, then Eq.9 partials ----
        const int concept = ct * CT + tc;
#pragma unroll
        for (int r = 0; r < 8; ++r) {
            float esum = 0.0f, ssum = 0.0f;
#pragma unroll
            for (int m = 0; m < 8; ++m) {
                float s = acc[r][m];
                float e = __expf(GAMMA_T * s);   // s in [-1,1] -> no overflow
                esum += e;
                ssum += e * s;
            }
            float simc = ssum / esum;
            denomp[r] += __expf(LAMBDA_T * simc);
            int rowg = rowbase + tr * 8 + r;
            if (concept == (rowg & (KK - 1))) simposv[r] = simc;  // positive concept
        }
    }

    // ---- per-row reduction across the 32 concept-threads ----
#pragma unroll
    for (int r = 0; r < 8; ++r) {
        atomicAdd(&sh_denom[tr * 8 + r], denomp[r]);
        int rowg = rowbase + tr * 8 + r;
        if ((rowg & 31) == tc)                 // unique owner thread per row
            sh_simpos[tr * 8 + r] = simposv[r];
    }
    __syncthreads();

    if (tid < ROW_TILE) {  // exactly wave 0
        float denom  = sh_denom[tid] + 1e-8f;
        float simpos = sh_simpos[tid] + MARGIN_T;
        float loss   = logf(denom) - LAMBDA_T * simpos;
        int   lbl    = labels[rowbase + tid];
        float mk     = (lbl == 1) ? 1.0f : 0.0f;
        float s = loss * mk;
        float c = mk;
#pragma unroll
        for (int off = 32; off >= 1; off >>= 1) {
            s += __shfl_down(s, off);
            c += __shfl_down(c, off);
        }
        if (tid == 0) {
            atomicAdd(&acc_ws[0], s);
            atomicAdd(&acc_ws[1], c);
        }
    }
}

__global__ void mpcl_final(const float* __restrict__ acc_ws, float* __restrict__ out)
{
    float t = acc_ws[0];
    float c = acc_ws[1];
    out[0] = (c > 0.0f) ? (t / c) : t;
}

extern "C" void kernel_launch(void* const* d_in, const int* in_sizes, int n_in,
                              void* d_out, int out_size, void* d_ws, size_t ws_size,
                              hipStream_t stream)
{
    // setup_inputs order: v_proj (f32), concept_labels (int), prototypes (f32)
    const float* V      = (const float*)d_in[0];
    const int*   labels = (const int*)d_in[1];
    const float* P      = (const float*)d_in[2];
    float* out = (float*)d_out;
    float* ws  = (float*)d_ws;

    hipMemsetAsync(ws, 0, 2 * sizeof(float), stream);
    mpcl_main<<<NROWS / ROW_TILE, 256, 0, stream>>>(V, labels, P, ws);
    mpcl_final<<<1, 1, 0, stream>>>(ws, out);
}

// Round 2
// 130.827 us; speedup vs baseline: 2.1559x; 2.1559x over previous
//
#include <hip/hip_runtime.h>

// B=128, K=256, M=8, D=128 ; rows = B*K = 32768 flattened (b,k)
#define NROWS 32768
#define LT 20.0f   // lambda and gamma are both 20

typedef _Float16 half8 __attribute__((ext_vector_type(8)));
typedef float    f32x4 __attribute__((ext_vector_type(4)));

__device__ __forceinline__ float swz16(float x) {
    // xor lane^16 within 32-lane halves (BitMode: xor=16, and=0x1F)
    return __int_as_float(__builtin_amdgcn_ds_swizzle(__float_as_int(x), 0x401F));
}

// Block: 512 threads = 8 waves; 128 rows/block; 256 blocks.
// wave w: half = w>>2 selects 64 rows, colq = w&3 selects a 16-wide P-column quarter per chunk.
// MFMA: A = P (M=16 cols = 2 concepts x 8 protos), B = V (N=16 batch rows), K=32 f16.
__global__ __launch_bounds__(512, 2)
void mpcl_main(const float* __restrict__ V,       // (32768, 128)
               const int*   __restrict__ labels,  // (32768)
               const float* __restrict__ P,       // (2048, 128)  [concept*8+m][d]
               float* __restrict__ acc_ws)        // [0]=loss sum, [1]=num_pos
{
    __shared__ _Float16 Pst[64 * 128];   // 16 KB chunk, XOR-swizzled dblk layout
    __shared__ float sh_denom[128];
    __shared__ float sh_simpos[128];

    const int tid  = threadIdx.x;
    const int lane = tid & 63;
    const int w    = tid >> 6;
    const int half = w >> 2;          // 0..1 row half
    const int colq = w & 3;           // 0..3 column quarter
    const int n    = lane & 15;
    const int q    = lane >> 4;       // quad
    const int rowbase = blockIdx.x * 128;
    const int cb   = colq * 16;       // col offset within 64-col chunk

    if (tid < 128) sh_denom[tid] = 0.0f;

    // ---- V fragments (B operand), exact f16 hi+lo split, register-resident ----
    half8 vhi[4][4], vlo[4][4];
#pragma unroll
    for (int rf = 0; rf < 4; ++rf) {
        const float* vr = V + (size_t)(rowbase + half * 64 + rf * 16 + n) * 128 + q * 8;
#pragma unroll
        for (int c = 0; c < 4; ++c) {
            float4 x0 = *(const float4*)(vr + c * 32);
            float4 x1 = *(const float4*)(vr + c * 32 + 4);
            float xs[8] = {x0.x, x0.y, x0.z, x0.w, x1.x, x1.y, x1.z, x1.w};
#pragma unroll
            for (int j = 0; j < 8; ++j) {
                _Float16 h = (_Float16)xs[j];
                vhi[rf][c][j] = h;
                vlo[rf][c][j] = (_Float16)(xs[j] - (float)h);
            }
        }
    }

    // ---- staging indices: thread covers 2 dblks (16 d) of one col ----
    const int scol = tid >> 3;        // 0..63
    const int sdb  = (tid & 7) * 2;   // dblk base (dblk = d/8, 0..15)

    float4 pf[4];
    {
        const float* pp = P + (size_t)scol * 128 + sdb * 8;   // chunk 0
        pf[0] = *(const float4*)(pp);
        pf[1] = *(const float4*)(pp + 4);
        pf[2] = *(const float4*)(pp + 8);
        pf[3] = *(const float4*)(pp + 12);
    }

    float dn[4] = {0.f, 0.f, 0.f, 0.f};

#pragma unroll 1
    for (int ch = 0; ch < 32; ++ch) {
        __syncthreads();   // consumers of previous chunk done
        // convert f32 -> f16 and write swizzled
#pragma unroll
        for (int p = 0; p < 2; ++p) {
            int dblk = sdb + p;
            int dbs  = (dblk & 8) | ((dblk ^ scol) & 7);
            float4 a = pf[2 * p], b = pf[2 * p + 1];
            half8 hv;
            hv[0] = (_Float16)a.x; hv[1] = (_Float16)a.y;
            hv[2] = (_Float16)a.z; hv[3] = (_Float16)a.w;
            hv[4] = (_Float16)b.x; hv[5] = (_Float16)b.y;
            hv[6] = (_Float16)b.z; hv[7] = (_Float16)b.w;
            *(half8*)&Pst[scol * 128 + dbs * 8] = hv;
        }
        __syncthreads();   // chunk staged

        // prefetch next chunk now: overlaps the MFMA block, drains at next barrier
        if (ch < 31) {
            const float* pp = P + (size_t)((ch + 1) * 64 + scol) * 128 + sdb * 8;
            pf[0] = *(const float4*)(pp);
            pf[1] = *(const float4*)(pp + 4);
            pf[2] = *(const float4*)(pp + 8);
            pf[3] = *(const float4*)(pp + 12);
        }

        // P fragments (A operand): lane n -> col cb+n, k = q*8+j within 32-k chunk c
        half8 pf16[4];
#pragma unroll
        for (int c = 0; c < 4; ++c) {
            int dblk = c * 4 + q;
            int col  = cb + n;
            int dbs  = (dblk & 8) | ((dblk ^ col) & 7);
            pf16[c] = *(const half8*)&Pst[col * 128 + dbs * 8];
        }

        f32x4 acc[4] = {{0.f,0.f,0.f,0.f},{0.f,0.f,0.f,0.f},
                        {0.f,0.f,0.f,0.f},{0.f,0.f,0.f,0.f}};
#pragma unroll
        for (int c = 0; c < 4; ++c)
#pragma unroll
            for (int rf = 0; rf < 4; ++rf) {
                acc[rf] = __builtin_amdgcn_mfma_f32_16x16x32_f16(pf16[c], vhi[rf][c], acc[rf], 0, 0, 0);
                acc[rf] = __builtin_amdgcn_mfma_f32_16x16x32_f16(pf16[c], vlo[rf][c], acc[rf], 0, 0, 0);
            }

        // ---- epilogue: softmax over m (4 in-lane + xor16), logsumexp partials ----
        const int cbase = ch * 8 + colq * 2;
        const int cA    = cbase + (q >> 1);      // this lane's concept
#pragma unroll
        for (int rf = 0; rf < 4; ++rf) {
            float s0 = acc[rf][0], s1 = acc[rf][1], s2 = acc[rf][2], s3 = acc[rf][3];
            float e0 = __expf(LT * s0), e1 = __expf(LT * s1);
            float e2 = __expf(LT * s2), e3 = __expf(LT * s3);
            float es = (e0 + e1) + (e2 + e3);
            float ss = fmaf(e0, s0, fmaf(e1, s1, fmaf(e2, s2, e3 * s3)));
            es += swz16(es);                     // combine m 0-3 with m 4-7
            ss += swz16(ss);
            float simc = __fdividef(ss, es);     // = sum(q*s), softmax-weighted sim
            dn[rf] += __expf(LT * simc);
            int rowloc = half * 64 + rf * 16 + n;
            int rowg   = rowbase + rowloc;
            if (cA == (rowg & 255) && (q & 1) == 0)
                sh_simpos[rowloc] = simc;        // unique writer per row
        }
    }

    // ---- fold per-lane denominators: q-pairs hold duplicated concepts -> /2 ----
#pragma unroll
    for (int rf = 0; rf < 4; ++rf) {
        float t = dn[rf];
        t += swz16(t);
        t += __shfl_xor(t, 32);
        if (q == 0)
            atomicAdd(&sh_denom[half * 64 + rf * 16 + n], 0.5f * t);
    }
    __syncthreads();

    if (tid < 128) {
        float denom = sh_denom[tid] + 1e-8f;
        float lp = logf(denom) - LT * (sh_simpos[tid] + 0.05f);
        float mk = (labels[rowbase + tid] == 1) ? 1.0f : 0.0f;
        float s = lp * mk;
        float c = mk;
#pragma unroll
        for (int off = 32; off >= 1; off >>= 1) {
            s += __shfl_down(s, off);
            c += __shfl_down(c, off);
        }
        if ((tid & 63) == 0) {
            atomicAdd(&acc_ws[0], s);
            atomicAdd(&acc_ws[1], c);
        }
    }
}

__global__ void mpcl_final(const float* __restrict__ acc_ws, float* __restrict__ out)
{
    float t = acc_ws[0];
    float c = acc_ws[1];
    out[0] = (c > 0.0f) ? (t / c) : t;
}

extern "C" void kernel_launch(void* const* d_in, const int* in_sizes, int n_in,
                              void* d_out, int out_size, void* d_ws, size_t ws_size,
                              hipStream_t stream)
{
    const float* V      = (const float*)d_in[0];
    const int*   labels = (const int*)d_in[1];
    const float* P      = (const float*)d_in[2];
    float* out = (float*)d_out;
    float* ws  = (float*)d_ws;

    hipMemsetAsync(ws, 0, 2 * sizeof(float), stream);
    mpcl_main<<<NROWS / 128, 512, 0, stream>>>(V, labels, P, ws);
    mpcl_final<<<1, 1, 0, stream>>>(ws, out);
}